// Round 1
// baseline (162.227 us; speedup 1.0000x reference)
//
#include <hip/hip_runtime.h>
#include <math.h>

#define NUM_CLASSES 10

// ---- block reduction: wave shuffle (64) -> LDS across waves -> lane 0 ----
__device__ __forceinline__ double block_reduce_sum(double v) {
    #pragma unroll
    for (int off = 32; off > 0; off >>= 1)
        v += __shfl_down(v, off, 64);
    __shared__ double lds[8];
    int lane = threadIdx.x & 63;
    int wid  = threadIdx.x >> 6;
    int nw   = blockDim.x >> 6;
    if (lane == 0) lds[wid] = v;
    __syncthreads();
    if (wid == 0) {
        v = (lane < nw) ? lds[lane] : 0.0;
        #pragma unroll
        for (int off = 4; off > 0; off >>= 1)
            v += __shfl_down(v, off, 64);
    }
    return v;
}

// ---- focal loss over B rows of C=10 logits ----
__global__ void focal_kernel(const float* __restrict__ logits,
                             const int*   __restrict__ targets,
                             const int*   __restrict__ tissue,
                             const float* __restrict__ cw,
                             const float* __restrict__ tw,
                             int B, double* __restrict__ acc) {
    double local = 0.0;
    for (int r = blockIdx.x * blockDim.x + threadIdx.x; r < B;
         r += gridDim.x * blockDim.x) {
        const float* row = logits + (size_t)r * NUM_CLASSES;
        float l[NUM_CLASSES];
        float m = -INFINITY;
        #pragma unroll
        for (int c = 0; c < NUM_CLASSES; ++c) { l[c] = row[c]; m = fmaxf(m, l[c]); }
        float s = 0.f;
        #pragma unroll
        for (int c = 0; c < NUM_CLASSES; ++c) s += expf(l[c] - m);
        int   t  = targets[r];
        float lp = l[t] - m - logf(s);       // log p_t
        float p  = expf(lp);
        float om = 1.f - p;
        float w  = om * om * cw[t] * tw[tissue[r]];
        local += (double)(-w * lp);
    }
    double v = block_reduce_sum(local);
    if (threadIdx.x == 0) atomicAdd(acc, v);
}

// ---- spatial regularization: sum_e dot(relu(S[src]),relu(S[dst])) * d2(e) ----
// identity: where(Si>0 & Sj>0, Si*Sj, 0) == relu(Si)*relu(Sj)
__global__ void spatial_kernel(const float* __restrict__ S,
                               const float* __restrict__ pos,
                               const int*   __restrict__ src_idx,
                               const int*   __restrict__ dst_idx,
                               int E, double* __restrict__ acc) {
    double local = 0.0;
    for (int e = blockIdx.x * blockDim.x + threadIdx.x; e < E;
         e += gridDim.x * blockDim.x) {
        int s = src_idx[e];
        int d = dst_idx[e];
        const float4* Sr = (const float4*)(S + (size_t)s * 32);
        const float4* Dr = (const float4*)(S + (size_t)d * 32);
        float dot = 0.f;
        #pragma unroll
        for (int c = 0; c < 8; ++c) {
            float4 a = Sr[c];
            float4 b = Dr[c];
            dot += fmaxf(a.x, 0.f) * fmaxf(b.x, 0.f);
            dot += fmaxf(a.y, 0.f) * fmaxf(b.y, 0.f);
            dot += fmaxf(a.z, 0.f) * fmaxf(b.z, 0.f);
            dot += fmaxf(a.w, 0.f) * fmaxf(b.w, 0.f);
        }
        float2 ps = ((const float2*)pos)[s];
        float2 pd = ((const float2*)pos)[d];
        float dx = ps.x - pd.x;
        float dy = ps.y - pd.y;
        local += (double)(dot * (dx * dx + dy * dy));
    }
    double v = block_reduce_sum(local);
    if (threadIdx.x == 0) atomicAdd(acc, v);
}

// ---- combine: out = {total, cls, spatial} ----
__global__ void finalize_kernel(const double* __restrict__ acc,
                                float* __restrict__ out, int B, int E) {
    if (threadIdx.x == 0 && blockIdx.x == 0) {
        float cls = (float)(acc[0] / (double)B);
        float sp  = (float)(0.01 * acc[1] / (double)E);
        out[0] = cls + sp;
        out[1] = cls;
        out[2] = sp;
    }
}

extern "C" void kernel_launch(void* const* d_in, const int* in_sizes, int n_in,
                              void* d_out, int out_size, void* d_ws, size_t ws_size,
                              hipStream_t stream) {
    const float* logits  = (const float*)d_in[0];
    const int*   targets = (const int*)  d_in[1];
    const float* S       = (const float*)d_in[2];
    const float* pos     = (const float*)d_in[3];
    const int*   edge    = (const int*)  d_in[4];
    const int*   tissue  = (const int*)  d_in[5];
    const float* cw      = (const float*)d_in[6];
    const float* tw      = (const float*)d_in[7];
    float* out = (float*)d_out;

    int B = in_sizes[1];
    int E = in_sizes[4] / 2;

    double* acc = (double*)d_ws;  // acc[0]=cls sum, acc[1]=spatial sum
    hipMemsetAsync(d_ws, 0, 2 * sizeof(double), stream);

    focal_kernel<<<16, 256, 0, stream>>>(logits, targets, tissue, cw, tw, B, acc + 0);
    spatial_kernel<<<2048, 256, 0, stream>>>(S, pos, edge, edge + E, E, acc + 1);
    finalize_kernel<<<1, 64, 0, stream>>>(acc, out, B, E);
}